// Round 1
// baseline (1253.223 us; speedup 1.0000x reference)
//
#include <hip/hip_runtime.h>
#include <cstddef>

// Problem constants (match reference setup_inputs)
#define HH    128
#define WW    128
#define CC    392           // K*K*8 = 49*8
#define NPIX  (HH*WW)       // 16384
#define NROI  2048
#define PSK   7
#define NBIN  49
#define LAMDA 0.1f

// Conv implicit-GEMM tiling: M=16384, N=392, K = 9 segments x 392 (pad->416)
#define BM 64
#define BN 64
#define BK 32
#define SEGP 416            // 13*32, zero-padded per-segment K
#define NCHUNK (9 * 13)     // 117 K-chunks of 32

// ---------------------------------------------------------------------------
// 3x3 SAME conv as shifted GEMM: OM[y,x,co] = sum_{ky,kx,ci} F[y+ky-1,x+kx-1,ci]*W[ky,kx,ci,co]
// A is im2col (virtual): A[m][seg*SEGP+ci] = F[(y+dy)*W + x+dx][ci] (0 if OOB / ci>=392)
// ---------------------------------------------------------------------------
__global__ __launch_bounds__(256)
void conv3x3_kernel(const float* __restrict__ F, const float* __restrict__ Wt,
                    float* __restrict__ OM) {
  __shared__ float As[BK][BM + 4];  // k-major so per-thread A reads are float4; +4 keeps 16B align
  __shared__ float Bs[BK][BN + 4];

  const int t = threadIdx.x;
  const int ty = t >> 4;            // 0..15 -> output rows ty*4..ty*4+3
  const int tx = t & 15;            // 0..15 -> output cols tx*4..tx*4+3
  const int row0 = blockIdx.x * BM; // M block (256 blocks, exact)
  const int col0 = blockIdx.y * BN; // N block (7 blocks, last masked)

  float acc[4][4];
#pragma unroll
  for (int i = 0; i < 4; ++i)
#pragma unroll
    for (int j = 0; j < 4; ++j) acc[i][j] = 0.f;

  for (int kc = 0; kc < NCHUNK; ++kc) {
    const int seg   = kc / 13;             // 0..8 -> (ky,kx)
    const int cbase = (kc - seg * 13) * BK;
    const int dy    = seg / 3 - 1;
    const int dx    = seg - (seg / 3) * 3 - 1;

    // ---- stage A tile: 64 rows x 32 ci, coalesced over ci ----
#pragma unroll
    for (int rep = 0; rep < (BM * BK) / 256; ++rep) {
      const int idx = t + rep * 256;
      const int r  = idx >> 5;             // tile row
      const int lk = idx & 31;             // k within chunk
      const int m  = row0 + r;
      const int y  = m >> 7, x = m & 127;
      const int yy = y + dy, xx = x + dx;
      const int ci = cbase + lk;
      float v = 0.f;
      if ((unsigned)yy < HH && (unsigned)xx < WW && ci < CC)
        v = F[((size_t)(yy * WW + xx)) * CC + ci];
      As[lk][r] = v;
    }
    // ---- stage B tile: 32 k x 64 n, coalesced over n ----
#pragma unroll
    for (int rep = 0; rep < (BK * BN) / 256; ++rep) {
      const int idx = t + rep * 256;
      const int lk  = idx >> 6;
      const int nn  = idx & 63;
      const int ci  = cbase + lk;
      const int col = col0 + nn;
      float v = 0.f;
      if (ci < CC && col < CC)
        v = Wt[((size_t)(seg * CC + ci)) * CC + col];
      Bs[lk][nn] = v;
    }
    __syncthreads();

#pragma unroll
    for (int lk = 0; lk < BK; ++lk) {
      const float4 a4 = *(const float4*)(&As[lk][ty * 4]);
      const float4 b4 = *(const float4*)(&Bs[lk][tx * 4]);
      const float av[4] = {a4.x, a4.y, a4.z, a4.w};
      const float bv[4] = {b4.x, b4.y, b4.z, b4.w};
#pragma unroll
      for (int i = 0; i < 4; ++i)
#pragma unroll
        for (int j = 0; j < 4; ++j)
          acc[i][j] = fmaf(av[i], bv[j], acc[i][j]);
    }
    __syncthreads();
  }

  // store: 392 % 4 == 0, so every float4 is fully valid or fully invalid
  const int col = col0 + tx * 4;
  if (col < CC) {
#pragma unroll
    for (int i = 0; i < 4; ++i) {
      float4 v = make_float4(acc[i][0], acc[i][1], acc[i][2], acc[i][3]);
      *(float4*)(&OM[((size_t)(row0 + ty * 4 + i)) * CC + col]) = v;
    }
  }
}

// ---------------------------------------------------------------------------
// Fused: stage-1 PS-RoI pool of OM (8 offset ch per bin) -> scale -> deformable
// PS-RoI pool of features. One thread per (roi, bin).
// ---------------------------------------------------------------------------
__device__ __forceinline__ void bilin_setup(float y, float x,
                                            int& iy0, int& iy1, int& ix0, int& ix1,
                                            float& w00, float& w01, float& w10, float& w11) {
  const float y0f = floorf(y), x0f = floorf(x);
  const float wy = y - y0f, wx = x - x0f;       // in [0,1), same as reference (unclamped)
  const int a = (int)y0f, b = (int)x0f;
  iy0 = min(max(a, 0), HH - 1);
  iy1 = min(max(a + 1, 0), HH - 1);
  ix0 = min(max(b, 0), WW - 1);
  ix1 = min(max(b + 1, 0), WW - 1);
  w00 = (1.f - wy) * (1.f - wx);
  w01 = (1.f - wy) * wx;
  w10 = wy * (1.f - wx);
  w11 = wy * wx;
}

__global__ __launch_bounds__(256)
void psroi_offset_pool_kernel(const float* __restrict__ F, const float* __restrict__ R,
                              const float* __restrict__ OM, float* __restrict__ out) {
  const int tid = blockIdx.x * 256 + threadIdx.x;
  if (tid >= NROI * NBIN) return;
  const int n = tid / NBIN;
  const int b = tid - n * NBIN;
  const int bi = b / PSK;
  const int bj = b - bi * PSK;

  const float rx1 = R[n * 5 + 1], ry1 = R[n * 5 + 2];
  const float rx2 = R[n * 5 + 3], ry2 = R[n * 5 + 4];

  const float x1 = rx1 * (1.f / 16.f);
  const float y1 = ry1 * (1.f / 16.f);
  const float x2 = (rx2 + 1.f) * (1.f / 16.f);
  const float y2 = (ry2 + 1.f) * (1.f / 16.f);
  const float bw = (x2 - x1) / 7.f;
  const float bh = (y2 - y1) / 7.f;
  const float cx = x1 + ((float)bj + 0.5f) * bw;
  const float cy = y1 + ((float)bi + 0.5f) * bh;

  // ---- stage 1: bilinear sample OM channels [b*8 .. b*8+7] at (cy,cx) ----
  int iy0, iy1, ix0, ix1;
  float w00, w01, w10, w11;
  bilin_setup(cy, cx, iy0, iy1, ix0, ix1, w00, w01, w10, w11);

  const size_t c8 = (size_t)b * 8;
  const float* p00 = OM + ((size_t)(iy0 * WW + ix0)) * CC + c8;
  const float* p01 = OM + ((size_t)(iy0 * WW + ix1)) * CC + c8;
  const float* p10 = OM + ((size_t)(iy1 * WW + ix0)) * CC + c8;
  const float* p11 = OM + ((size_t)(iy1 * WW + ix1)) * CC + c8;

  float o[8];
#pragma unroll
  for (int h = 0; h < 2; ++h) {   // two float4 halves, channels are bin-contiguous
    const float4 v00 = *(const float4*)(p00 + 4 * h);
    const float4 v01 = *(const float4*)(p01 + 4 * h);
    const float4 v10 = *(const float4*)(p10 + 4 * h);
    const float4 v11 = *(const float4*)(p11 + 4 * h);
    o[4 * h + 0] = w00 * v00.x + w01 * v01.x + w10 * v10.x + w11 * v11.x;
    o[4 * h + 1] = w00 * v00.y + w01 * v01.y + w10 * v10.y + w11 * v11.y;
    o[4 * h + 2] = w00 * v00.z + w01 * v01.z + w10 * v10.z + w11 * v11.z;
    o[4 * h + 3] = w00 * v00.w + w01 * v01.w + w10 * v10.w + w11 * v11.w;
  }

  const float roiw = rx2 - rx1 + 1.f;
  const float roih = ry2 - ry1 + 1.f;
  const float sxs = roiw * (LAMDA / 16.f);  // offsets are image-coord, /feat_stride
  const float sys = roih * (LAMDA / 16.f);

  // ---- stage 2: deformable sample of features, groups g=0..3, 2 ch each ----
#pragma unroll
  for (int g = 0; g < 4; ++g) {
    const float sx = cx + o[2 * g] * sxs;
    const float sy = cy + o[2 * g + 1] * sys;
    int jy0, jy1, jx0, jx1;
    float u00, u01, u10, u11;
    bilin_setup(sy, sx, jy0, jy1, jx0, jx1, u00, u01, u10, u11);

    const size_t c0 = (size_t)b * 8 + 2 * g;
    const float2 q00 = *(const float2*)(F + ((size_t)(jy0 * WW + jx0)) * CC + c0);
    const float2 q01 = *(const float2*)(F + ((size_t)(jy0 * WW + jx1)) * CC + c0);
    const float2 q10 = *(const float2*)(F + ((size_t)(jy1 * WW + jx0)) * CC + c0);
    const float2 q11 = *(const float2*)(F + ((size_t)(jy1 * WW + jx1)) * CC + c0);

    const float v0 = u00 * q00.x + u01 * q01.x + u10 * q10.x + u11 * q11.x;
    const float v1 = u00 * q00.y + u01 * q01.y + u10 * q10.y + u11 * q11.y;

    // out[n, d, i, j] with d = 2g+c, flat = (n*8 + d)*49 + b
    out[((size_t)n * 8 + 2 * g + 0) * NBIN + b] = v0;
    out[((size_t)n * 8 + 2 * g + 1) * NBIN + b] = v1;
  }
}

extern "C" void kernel_launch(void* const* d_in, const int* in_sizes, int n_in,
                              void* d_out, int out_size, void* d_ws, size_t ws_size,
                              hipStream_t stream) {
  const float* F  = (const float*)d_in[0];   // features [1,128,128,392] fp32
  const float* R  = (const float*)d_in[1];   // rois [2048,5] fp32
  const float* Wt = (const float*)d_in[2];   // conv_w [3,3,392,392] fp32
  float* out = (float*)d_out;                // [2048,8,7,7] fp32

  float* OM = (float*)d_ws;                  // offset_map [16384,392] fp32 = 25.7 MB

  dim3 cgrid(NPIX / BM, (CC + BN - 1) / BN); // 256 x 7
  conv3x3_kernel<<<cgrid, 256, 0, stream>>>(F, Wt, OM);

  const int total = NROI * NBIN;
  psroi_offset_pool_kernel<<<(total + 255) / 256, 256, 0, stream>>>(F, R, OM, out);
}

// Round 2
// 193.680 us; speedup vs baseline: 6.4706x; 6.4706x over previous
//
#include <hip/hip_runtime.h>
#include <cstddef>
#include <cstdint>

// Problem constants (match reference setup_inputs)
#define HH    128
#define WW    128
#define CC    392           // K*K*8 = 49*8
#define NPIX  (HH*WW)       // 16384
#define NROI  2048
#define PSK   7
#define NBIN  49
#define LAMDA 0.1f

// MFMA conv layout constants
#define CPAD      416       // channels padded to 13*32
#define HPAD      130       // 128 + 1px zero halo each side
#define NPADCO    512       // output channels padded to 4 N-blocks of 128
#define SEGSTRIDE (9*CPAD)  // 3744 elems per co row in Bth

// Fallback fp32 conv tiling (round-1 kernel, used only if ws too small)
#define BM 64
#define BN 64
#define BK 32

typedef _Float16 half8  __attribute__((ext_vector_type(8)));
typedef float    floatx4 __attribute__((ext_vector_type(4)));

// ---------------------------------------------------------------------------
// async global->LDS 16B (dest = wave-uniform base + lane*16)
// ---------------------------------------------------------------------------
__device__ __forceinline__ void async_ld16(const _Float16* g, _Float16* l) {
  __builtin_amdgcn_global_load_lds((const __attribute__((address_space(1))) void*)g,
                                   (__attribute__((address_space(3))) void*)l,
                                   16, 0, 0);
}

// ---------------------------------------------------------------------------
// Pre-pass 1: features fp32 [128,128,392] -> f16 [130,130,416] w/ zero halo+pad
// ---------------------------------------------------------------------------
__global__ __launch_bounds__(256)
void conv_f_kernel(const float* __restrict__ F, _Float16* __restrict__ Fh) {
  const int idx = blockIdx.x * 256 + threadIdx.x;
  const int total = HPAD * HPAD * CPAD;
  if (idx >= total) return;
  const int p = idx / CPAD;
  const int c = idx - p * CPAD;
  const int py = p / HPAD;
  const int px = p - py * HPAD;
  float v = 0.f;
  if (py >= 1 && py <= HH && px >= 1 && px <= WW && c < CC)
    v = F[((size_t)(py - 1) * WW + (px - 1)) * CC + c];
  Fh[idx] = (_Float16)v;
}

// ---------------------------------------------------------------------------
// Pre-pass 2: weights fp32 [9,392,392] (seg,ci,co) -> f16 Bth[co][seg][ci']
// co padded to 512, ci padded to 416 (zeros). Source reads are strided but the
// 5.5 MB source is L2/L3-resident after first touch.
// ---------------------------------------------------------------------------
__global__ __launch_bounds__(256)
void conv_w_kernel(const float* __restrict__ Wt, _Float16* __restrict__ Bth) {
  const int idx = blockIdx.x * 256 + threadIdx.x;
  const int total = NPADCO * SEGSTRIDE;
  if (idx >= total) return;
  const int co = idx / SEGSTRIDE;
  const int r = idx - co * SEGSTRIDE;
  const int seg = r / CPAD;
  const int ci = r - seg * CPAD;
  float v = 0.f;
  if (co < CC && ci < CC)
    v = Wt[((size_t)seg * CC + ci) * CC + co];
  Bth[idx] = (_Float16)v;
}

// ---------------------------------------------------------------------------
// MFMA implicit-GEMM 3x3 conv: M=16384 (pixels), N=512 (co, masked to 392),
// K = 9 segs x 416 ci. 128x128 block tile, BK=32, 4 waves 2x2, wave 64x64 =
// 4x4 mfma_f32_16x16x32_f16 (m97 structure). Staging via global_load_lds x16B.
// ---------------------------------------------------------------------------
__global__ __launch_bounds__(256, 3)
void conv_mfma_kernel(const _Float16* __restrict__ Fh, const _Float16* __restrict__ Bth,
                      _Float16* __restrict__ OM) {
  __shared__ __align__(16) _Float16 As[128 * 32];
  __shared__ __align__(16) _Float16 Bs[128 * 32];

  const int t = threadIdx.x;
  const int L = t & 63;
  const int w = t >> 6;
  const int row0 = blockIdx.x * 128;   // pixel block
  const int col0 = blockIdx.y * 128;   // co block

  // staging: wave w stages A rows [w*32, w*32+32) and B rows [w*32, w*32+32)
  // each 1KB wave-load covers 16 rows x 64B; lane L -> row L>>2, k-part L&3
  const int rl = L >> 2;
  const int kp = (L & 3) * 8;

  const int mA0 = row0 + w * 32 + rl;
  const int mA1 = mA0 + 16;
  const int yA0 = (mA0 >> 7) + 1, xA0 = (mA0 & 127) + 1;  // +1 halo
  const int yA1 = (mA1 >> 7) + 1, xA1 = (mA1 & 127) + 1;

  const int nB0 = col0 + w * 32 + rl;
  const _Float16* gB0base = Bth + (size_t)nB0 * SEGSTRIDE + kp;
  const _Float16* gB1base = gB0base + (size_t)16 * SEGSTRIDE;

  _Float16* lA0 = &As[(w * 32) * 32];
  _Float16* lA1 = &As[(w * 32 + 16) * 32];
  _Float16* lB0 = &Bs[(w * 32) * 32];
  _Float16* lB1 = &Bs[(w * 32 + 16) * 32];

  // compute: waves 2x2, wave tile 64x64
  const int wm = (w >> 1) * 64;
  const int wn = (w & 1) * 64;
  const int fr = L & 15;          // row/col within 16-tile
  const int fk = (L >> 4) * 8;    // k elem offset (quad*8)

  floatx4 acc[4][4];
#pragma unroll
  for (int i = 0; i < 4; ++i)
#pragma unroll
    for (int j = 0; j < 4; ++j) {
      floatx4 z = {0.f, 0.f, 0.f, 0.f};
      acc[i][j] = z;
    }

  for (int seg = 0; seg < 9; ++seg) {
    const int dy = seg / 3 - 1;
    const int dx = seg - (seg / 3) * 3 - 1;
    const _Float16* gA0 = Fh + (size_t)((yA0 + dy) * HPAD + (xA0 + dx)) * CPAD + kp;
    const _Float16* gA1 = Fh + (size_t)((yA1 + dy) * HPAD + (xA1 + dx)) * CPAD + kp;
    const _Float16* gB0 = gB0base + seg * CPAD;
    const _Float16* gB1 = gB1base + seg * CPAD;

    for (int cb = 0; cb < 13; ++cb) {
      const int cbase = cb * 32;
      async_ld16(gA0 + cbase, lA0);
      async_ld16(gA1 + cbase, lA1);
      async_ld16(gB0 + cbase, lB0);
      async_ld16(gB1 + cbase, lB1);
      __syncthreads();   // drains vmcnt -> LDS tiles ready

      half8 a[4], b[4];
#pragma unroll
      for (int mt = 0; mt < 4; ++mt)
        a[mt] = *(const half8*)(&As[(wm + mt * 16 + fr) * 32 + fk]);
#pragma unroll
      for (int nt = 0; nt < 4; ++nt)
        b[nt] = *(const half8*)(&Bs[(wn + nt * 16 + fr) * 32 + fk]);
#pragma unroll
      for (int mt = 0; mt < 4; ++mt)
#pragma unroll
        for (int nt = 0; nt < 4; ++nt)
          acc[mt][nt] = __builtin_amdgcn_mfma_f32_16x16x32_f16(a[mt], b[nt], acc[mt][nt], 0, 0, 0);
      __syncthreads();   // protect LDS before next chunk's staging
    }
  }

  // epilogue: C/D mapping col=lane&15, row=(lane>>4)*4+reg; store f16, mask col<392
#pragma unroll
  for (int mt = 0; mt < 4; ++mt) {
    const int rbase = row0 + wm + mt * 16 + (L >> 4) * 4;
#pragma unroll
    for (int nt = 0; nt < 4; ++nt) {
      const int col = col0 + wn + nt * 16 + fr;
      if (col < CC) {
#pragma unroll
        for (int r = 0; r < 4; ++r)
          OM[(size_t)(rbase + r) * CC + col] = (_Float16)acc[mt][nt][r];
      }
    }
  }
}

// ---------------------------------------------------------------------------
// Fallback fp32 conv (round-1 kernel) — used only if ws_size is too small
// ---------------------------------------------------------------------------
__global__ __launch_bounds__(256)
void conv3x3_kernel(const float* __restrict__ F, const float* __restrict__ Wt,
                    float* __restrict__ OM) {
  __shared__ float Asf[BK][BM + 4];
  __shared__ float Bsf[BK][BN + 4];

  const int t = threadIdx.x;
  const int ty = t >> 4;
  const int tx = t & 15;
  const int row0 = blockIdx.x * BM;
  const int col0 = blockIdx.y * BN;

  float acc[4][4];
#pragma unroll
  for (int i = 0; i < 4; ++i)
#pragma unroll
    for (int j = 0; j < 4; ++j) acc[i][j] = 0.f;

  for (int kc = 0; kc < 117; ++kc) {
    const int seg   = kc / 13;
    const int cbase = (kc - seg * 13) * BK;
    const int dy    = seg / 3 - 1;
    const int dx    = seg - (seg / 3) * 3 - 1;

#pragma unroll
    for (int rep = 0; rep < (BM * BK) / 256; ++rep) {
      const int idx = t + rep * 256;
      const int r  = idx >> 5;
      const int lk = idx & 31;
      const int m  = row0 + r;
      const int y  = m >> 7, x = m & 127;
      const int yy = y + dy, xx = x + dx;
      const int ci = cbase + lk;
      float v = 0.f;
      if ((unsigned)yy < HH && (unsigned)xx < WW && ci < CC)
        v = F[((size_t)(yy * WW + xx)) * CC + ci];
      Asf[lk][r] = v;
    }
#pragma unroll
    for (int rep = 0; rep < (BK * BN) / 256; ++rep) {
      const int idx = t + rep * 256;
      const int lk  = idx >> 6;
      const int nn  = idx & 63;
      const int ci  = cbase + lk;
      const int col = col0 + nn;
      float v = 0.f;
      if (ci < CC && col < CC)
        v = Wt[((size_t)(seg * CC + ci)) * CC + col];
      Bsf[lk][nn] = v;
    }
    __syncthreads();

#pragma unroll
    for (int lk = 0; lk < BK; ++lk) {
      const float4 a4 = *(const float4*)(&Asf[lk][ty * 4]);
      const float4 b4 = *(const float4*)(&Bsf[lk][tx * 4]);
      const float av[4] = {a4.x, a4.y, a4.z, a4.w};
      const float bv[4] = {b4.x, b4.y, b4.z, b4.w};
#pragma unroll
      for (int i = 0; i < 4; ++i)
#pragma unroll
        for (int j = 0; j < 4; ++j)
          acc[i][j] = fmaf(av[i], bv[j], acc[i][j]);
    }
    __syncthreads();
  }

  const int col = col0 + tx * 4;
  if (col < CC) {
#pragma unroll
    for (int i = 0; i < 4; ++i) {
      float4 v = make_float4(acc[i][0], acc[i][1], acc[i][2], acc[i][3]);
      *(float4*)(&OM[((size_t)(row0 + ty * 4 + i)) * CC + col]) = v;
    }
  }
}

// ---------------------------------------------------------------------------
// Fused: stage-1 PS-RoI pool of OM (8 offset ch per bin) -> scale -> deformable
// PS-RoI pool of features. One thread per (roi, bin). TOM = f16 or f32.
// ---------------------------------------------------------------------------
__device__ __forceinline__ void bilin_setup(float y, float x,
                                            int& iy0, int& iy1, int& ix0, int& ix1,
                                            float& w00, float& w01, float& w10, float& w11) {
  const float y0f = floorf(y), x0f = floorf(x);
  const float wy = y - y0f, wx = x - x0f;
  const int a = (int)y0f, b = (int)x0f;
  iy0 = min(max(a, 0), HH - 1);
  iy1 = min(max(a + 1, 0), HH - 1);
  ix0 = min(max(b, 0), WW - 1);
  ix1 = min(max(b + 1, 0), WW - 1);
  w00 = (1.f - wy) * (1.f - wx);
  w01 = (1.f - wy) * wx;
  w10 = wy * (1.f - wx);
  w11 = wy * wx;
}

template <typename TOM>
__global__ __launch_bounds__(256)
void psroi_pool_kernel(const float* __restrict__ F, const float* __restrict__ R,
                       const TOM* __restrict__ OM, float* __restrict__ out) {
  const int tid = blockIdx.x * 256 + threadIdx.x;
  if (tid >= NROI * NBIN) return;
  const int n = tid / NBIN;
  const int b = tid - n * NBIN;
  const int bi = b / PSK;
  const int bj = b - bi * PSK;

  const float rx1 = R[n * 5 + 1], ry1 = R[n * 5 + 2];
  const float rx2 = R[n * 5 + 3], ry2 = R[n * 5 + 4];

  const float x1 = rx1 * (1.f / 16.f);
  const float y1 = ry1 * (1.f / 16.f);
  const float x2 = (rx2 + 1.f) * (1.f / 16.f);
  const float y2 = (ry2 + 1.f) * (1.f / 16.f);
  const float bw = (x2 - x1) / 7.f;
  const float bh = (y2 - y1) / 7.f;
  const float cx = x1 + ((float)bj + 0.5f) * bw;
  const float cy = y1 + ((float)bi + 0.5f) * bh;

  int iy0, iy1, ix0, ix1;
  float w00, w01, w10, w11;
  bilin_setup(cy, cx, iy0, iy1, ix0, ix1, w00, w01, w10, w11);

  const size_t c8 = (size_t)b * 8;
  const size_t o00 = (size_t)(iy0 * WW + ix0) * CC + c8;
  const size_t o01 = (size_t)(iy0 * WW + ix1) * CC + c8;
  const size_t o10 = (size_t)(iy1 * WW + ix0) * CC + c8;
  const size_t o11 = (size_t)(iy1 * WW + ix1) * CC + c8;

  float o[8];
  if constexpr (sizeof(TOM) == 2) {
    const half8 v00 = *(const half8*)(OM + o00);
    const half8 v01 = *(const half8*)(OM + o01);
    const half8 v10 = *(const half8*)(OM + o10);
    const half8 v11 = *(const half8*)(OM + o11);
#pragma unroll
    for (int i = 0; i < 8; ++i)
      o[i] = w00 * (float)v00[i] + w01 * (float)v01[i]
           + w10 * (float)v10[i] + w11 * (float)v11[i];
  } else {
#pragma unroll
    for (int h = 0; h < 2; ++h) {
      const float4 v00 = *(const float4*)(OM + o00 + 4 * h);
      const float4 v01 = *(const float4*)(OM + o01 + 4 * h);
      const float4 v10 = *(const float4*)(OM + o10 + 4 * h);
      const float4 v11 = *(const float4*)(OM + o11 + 4 * h);
      o[4 * h + 0] = w00 * v00.x + w01 * v01.x + w10 * v10.x + w11 * v11.x;
      o[4 * h + 1] = w00 * v00.y + w01 * v01.y + w10 * v10.y + w11 * v11.y;
      o[4 * h + 2] = w00 * v00.z + w01 * v01.z + w10 * v10.z + w11 * v11.z;
      o[4 * h + 3] = w00 * v00.w + w01 * v01.w + w10 * v10.w + w11 * v11.w;
    }
  }

  const float roiw = rx2 - rx1 + 1.f;
  const float roih = ry2 - ry1 + 1.f;
  const float sxs = roiw * (LAMDA / 16.f);
  const float sys = roih * (LAMDA / 16.f);

#pragma unroll
  for (int g = 0; g < 4; ++g) {
    const float sx = cx + o[2 * g] * sxs;
    const float sy = cy + o[2 * g + 1] * sys;
    int jy0, jy1, jx0, jx1;
    float u00, u01, u10, u11;
    bilin_setup(sy, sx, jy0, jy1, jx0, jx1, u00, u01, u10, u11);

    const size_t c0 = (size_t)b * 8 + 2 * g;
    const float2 q00 = *(const float2*)(F + (size_t)(jy0 * WW + jx0) * CC + c0);
    const float2 q01 = *(const float2*)(F + (size_t)(jy0 * WW + jx1) * CC + c0);
    const float2 q10 = *(const float2*)(F + (size_t)(jy1 * WW + jx0) * CC + c0);
    const float2 q11 = *(const float2*)(F + (size_t)(jy1 * WW + jx1) * CC + c0);

    const float v0 = u00 * q00.x + u01 * q01.x + u10 * q10.x + u11 * q11.x;
    const float v1 = u00 * q00.y + u01 * q01.y + u10 * q10.y + u11 * q11.y;

    out[((size_t)n * 8 + 2 * g + 0) * NBIN + b] = v0;
    out[((size_t)n * 8 + 2 * g + 1) * NBIN + b] = v1;
  }
}

extern "C" void kernel_launch(void* const* d_in, const int* in_sizes, int n_in,
                              void* d_out, int out_size, void* d_ws, size_t ws_size,
                              hipStream_t stream) {
  const float* F  = (const float*)d_in[0];   // features [1,128,128,392] fp32
  const float* R  = (const float*)d_in[1];   // rois [2048,5] fp32
  const float* Wt = (const float*)d_in[2];   // conv_w [3,3,392,392] fp32
  float* out = (float*)d_out;                // [2048,8,7,7] fp32

  const size_t omBytes16 = (size_t)NPIX * CC * sizeof(_Float16);        // 12.8 MB
  const size_t fhBytes   = (size_t)HPAD * HPAD * CPAD * sizeof(_Float16); // 14.1 MB
  const size_t bthBytes  = (size_t)NPADCO * SEGSTRIDE * sizeof(_Float16); // 3.8 MB
  const size_t need = omBytes16 + fhBytes + bthBytes;                   // 30.7 MB

  const int totalPool = NROI * NBIN;

  if (ws_size >= need) {
    _Float16* OM  = (_Float16*)d_ws;
    _Float16* Fh  = (_Float16*)((char*)d_ws + omBytes16);
    _Float16* Bth = (_Float16*)((char*)d_ws + omBytes16 + fhBytes);

    conv_f_kernel<<<(HPAD * HPAD * CPAD + 255) / 256, 256, 0, stream>>>(F, Fh);
    conv_w_kernel<<<(NPADCO * SEGSTRIDE + 255) / 256, 256, 0, stream>>>(Wt, Bth);

    dim3 g(NPIX / 128, NPADCO / 128);  // 128 x 4
    conv_mfma_kernel<<<g, 256, 0, stream>>>(Fh, Bth, OM);

    psroi_pool_kernel<_Float16><<<(totalPool + 255) / 256, 256, 0, stream>>>(F, R, OM, out);
  } else {
    // fallback: fp32 conv (round-1 path), needs 25.7 MB
    float* OM = (float*)d_ws;
    dim3 cgrid(NPIX / BM, (CC + BN - 1) / BN);
    conv3x3_kernel<<<cgrid, 256, 0, stream>>>(F, Wt, OM);
    psroi_pool_kernel<float><<<(totalPool + 255) / 256, 256, 0, stream>>>(F, R, OM, out);
  }
}

// Round 3
// 166.421 us; speedup vs baseline: 7.5305x; 1.1638x over previous
//
#include <hip/hip_runtime.h>
#include <cstddef>
#include <cstdint>

// Problem constants (match reference setup_inputs)
#define HH    128
#define WW    128
#define CC    392           // K*K*8 = 49*8
#define NPIX  (HH*WW)       // 16384
#define NROI  2048
#define PSK   7
#define NBIN  49
#define LAMDA 0.1f

// MFMA conv layout constants
#define CPAD      448       // channels padded to 7*64
#define HPAD      130       // 128 + 1px zero halo each side
#define NPADCO    512       // output channels padded to 4 N-blocks of 128
#define SEGSTRIDE (9*CPAD)  // 4032 elems per co row in Bth
#define BKK       64        // K-chunk per barrier

// Fallback fp32 conv tiling (round-1 kernel, used only if ws too small)
#define FBM 64
#define FBN 64
#define FBK 32

typedef _Float16 half8   __attribute__((ext_vector_type(8)));
typedef float    floatx4 __attribute__((ext_vector_type(4)));

// ---------------------------------------------------------------------------
// async global->LDS 16B (dest = wave-uniform base + lane*16)
// ---------------------------------------------------------------------------
__device__ __forceinline__ void async_ld16(const _Float16* g, _Float16* l) {
  __builtin_amdgcn_global_load_lds((const __attribute__((address_space(1))) void*)g,
                                   (__attribute__((address_space(3))) void*)l,
                                   16, 0, 0);
}

// ---------------------------------------------------------------------------
// Pre-pass 1: features fp32 [128,128,392] -> f16 [130,130,448] w/ zero halo+pad
// One thread per (padded pixel, 8-channel group): float4 x2 -> half8.
// ---------------------------------------------------------------------------
__global__ __launch_bounds__(256)
void conv_f_kernel(const float* __restrict__ F, _Float16* __restrict__ Fh) {
  const int idx = blockIdx.x * 256 + threadIdx.x;
  const int total = HPAD * HPAD * (CPAD / 8);
  if (idx >= total) return;
  const int p  = idx / (CPAD / 8);
  const int cg = idx - p * (CPAD / 8);
  const int c  = cg * 8;
  const int py = p / HPAD;
  const int px = p - py * HPAD;
  half8 h;
#pragma unroll
  for (int i = 0; i < 8; ++i) h[i] = (_Float16)0.f;
  if (py >= 1 && py <= HH && px >= 1 && px <= WW && c < CC) {
    const float* src = F + ((size_t)(py - 1) * WW + (px - 1)) * CC + c;
    const float4 v0 = *(const float4*)src;
    const float4 v1 = *(const float4*)(src + 4);
    h[0] = (_Float16)v0.x; h[1] = (_Float16)v0.y;
    h[2] = (_Float16)v0.z; h[3] = (_Float16)v0.w;
    h[4] = (_Float16)v1.x; h[5] = (_Float16)v1.y;
    h[6] = (_Float16)v1.z; h[7] = (_Float16)v1.w;
  }
  *(half8*)(Fh + (size_t)p * CPAD + c) = h;
}

// ---------------------------------------------------------------------------
// Pre-pass 2: weights fp32 [9,392,392] (seg,ci,co) -> f16 Bth[co][seg][ci']
// 32x32 LDS tile transpose: both global read (along co) and write (along ci)
// are coalesced. co padded to 512, ci padded to 448 (zeros).
// ---------------------------------------------------------------------------
__global__ __launch_bounds__(256)
void conv_w_kernel(const float* __restrict__ Wt, _Float16* __restrict__ Bth) {
  __shared__ float tile[32][33];
  const int bid = blockIdx.x;
  const int seg = bid / (14 * 16);
  const int rem = bid - seg * (14 * 16);
  const int cit = rem / 16;         // ci tile 0..13
  const int cot = rem - cit * 16;   // co tile 0..15
  const int ci0 = cit * 32, co0 = cot * 32;
  const int t = threadIdx.x;
#pragma unroll
  for (int i = 0; i < 4; ++i) {
    const int idx = t + i * 256;
    const int lr = idx >> 5;        // local ci
    const int lc = idx & 31;        // local co (fast -> coalesced read)
    const int ci = ci0 + lr, co = co0 + lc;
    float v = 0.f;
    if (ci < CC && co < CC) v = Wt[((size_t)seg * CC + ci) * CC + co];
    tile[lr][lc] = v;
  }
  __syncthreads();
#pragma unroll
  for (int i = 0; i < 4; ++i) {
    const int idx = t + i * 256;
    const int lr = idx >> 5;        // local co
    const int lc = idx & 31;        // local ci (fast -> coalesced write)
    Bth[(size_t)(co0 + lr) * SEGSTRIDE + seg * CPAD + ci0 + lc] = (_Float16)tile[lc][lr];
  }
}

// ---------------------------------------------------------------------------
// MFMA implicit-GEMM 3x3 conv: M=16384 (pixels), N=512 (co, masked to 392),
// K = 9 segs x 448 ci. 128x128 block tile, BK=64, 4 waves 2x2, wave 64x64 =
// 4x4 mfma_f32_16x16x32_f16 x 2 k-chunks per barrier.
//
// LDS swizzle: a tile row is 64 halves = 8 x 16B groups; logical group g of
// row r is stored at physical group g ^ (r & 7). Staging lane L (srow=L>>3,
// phys grp L&7) therefore FETCHES logical group (L&7)^srow; readers (quad
// q, row fr) read phys (c*4+q)^(fr&7). Bank base = phys*4 -> 2-way max = free.
// ---------------------------------------------------------------------------
__global__ __launch_bounds__(256, 2)
void conv_mfma_kernel(const _Float16* __restrict__ Fh, const _Float16* __restrict__ Bth,
                      _Float16* __restrict__ OM) {
  __shared__ __align__(16) _Float16 As[128 * BKK];  // 16 KB
  __shared__ __align__(16) _Float16 Bs[128 * BKK];  // 16 KB

  const int t = threadIdx.x;
  const int L = t & 63;
  const int w = t >> 6;
  const int row0 = blockIdx.x * 128;   // pixel block == image row y = blockIdx.x
  const int col0 = blockIdx.y * 128;   // co block

  // staging: wave w stages tile rows [w*32, w*32+32) of A and of B, 4 insts each.
  const int srow = L >> 3;                 // 0..7 (row within 8-row inst)
  const int kofs = ((L & 7) ^ srow) * 8;   // logical halves offset this lane fetches

  const int ya = row0 >> 7;                // image y for this whole M-tile
  const int nbase = col0 + w * 32 + srow;  // B: co of inst j adds j*8

  // compute-side fragment indexing
  const int wm = (w >> 1) * 64;
  const int wn = (w & 1) * 64;
  const int fr = L & 15;
  const int quad = L >> 4;
  const int pg0 = (quad ^ (fr & 7)) * 8;        // phys halves offset, k-chunk 0
  const int pg1 = ((4 + quad) ^ (fr & 7)) * 8;  // k-chunk 1

  floatx4 acc[4][4];
#pragma unroll
  for (int i = 0; i < 4; ++i)
#pragma unroll
    for (int j = 0; j < 4; ++j) {
      floatx4 z = {0.f, 0.f, 0.f, 0.f};
      acc[i][j] = z;
    }

  for (int seg = 0; seg < 9; ++seg) {
    const int dy = seg / 3 - 1;
    const int dx = seg - (seg / 3) * 3 - 1;
    const int fy = ya + 1 + dy;
    // A row for tile row xr (pixel x = xr): Fh[fy][1+dx+xr][.]
    const _Float16* gArow = Fh + ((size_t)fy * HPAD + (1 + dx)) * CPAD + kofs;
    const _Float16* gB = Bth + (size_t)nbase * SEGSTRIDE + seg * CPAD + kofs;

    for (int it = 0; it < 7; ++it) {
      const int cb = it * BKK;
#pragma unroll
      for (int j = 0; j < 4; ++j) {
        const int xr = w * 32 + j * 8 + srow;
        async_ld16(gArow + (size_t)xr * CPAD + cb, &As[(w * 32 + j * 8) * BKK]);
      }
#pragma unroll
      for (int j = 0; j < 4; ++j) {
        async_ld16(gB + (size_t)(j * 8) * SEGSTRIDE + cb, &Bs[(w * 32 + j * 8) * BKK]);
      }
      __syncthreads();   // drains vmcnt -> LDS tiles ready

      half8 a0[4], a1[4], b0[4], b1[4];
#pragma unroll
      for (int mt = 0; mt < 4; ++mt) {
        const int rb = (wm + mt * 16 + fr) * BKK;
        a0[mt] = *(const half8*)(&As[rb + pg0]);
        a1[mt] = *(const half8*)(&As[rb + pg1]);
      }
#pragma unroll
      for (int nt = 0; nt < 4; ++nt) {
        const int rb = (wn + nt * 16 + fr) * BKK;
        b0[nt] = *(const half8*)(&Bs[rb + pg0]);
        b1[nt] = *(const half8*)(&Bs[rb + pg1]);
      }
#pragma unroll
      for (int mt = 0; mt < 4; ++mt)
#pragma unroll
        for (int nt = 0; nt < 4; ++nt)
          acc[mt][nt] = __builtin_amdgcn_mfma_f32_16x16x32_f16(a0[mt], b0[nt], acc[mt][nt], 0, 0, 0);
#pragma unroll
      for (int mt = 0; mt < 4; ++mt)
#pragma unroll
        for (int nt = 0; nt < 4; ++nt)
          acc[mt][nt] = __builtin_amdgcn_mfma_f32_16x16x32_f16(a1[mt], b1[nt], acc[mt][nt], 0, 0, 0);
      __syncthreads();   // protect LDS before next chunk's staging
    }
  }

  // epilogue: C/D mapping col=lane&15, row=(lane>>4)*4+reg; store f16, mask col<392
#pragma unroll
  for (int mt = 0; mt < 4; ++mt) {
    const int rbase = row0 + wm + mt * 16 + quad * 4;
#pragma unroll
    for (int nt = 0; nt < 4; ++nt) {
      const int col = col0 + wn + nt * 16 + fr;
      if (col < CC) {
#pragma unroll
        for (int r = 0; r < 4; ++r)
          OM[(size_t)(rbase + r) * CC + col] = (_Float16)acc[mt][nt][r];
      }
    }
  }
}

// ---------------------------------------------------------------------------
// Fallback fp32 conv (round-1 kernel) — used only if ws_size is too small
// ---------------------------------------------------------------------------
__global__ __launch_bounds__(256)
void conv3x3_kernel(const float* __restrict__ F, const float* __restrict__ Wt,
                    float* __restrict__ OM) {
  __shared__ float Asf[FBK][FBM + 4];
  __shared__ float Bsf[FBK][FBN + 4];

  const int t = threadIdx.x;
  const int ty = t >> 4;
  const int tx = t & 15;
  const int row0 = blockIdx.x * FBM;
  const int col0 = blockIdx.y * FBN;

  float acc[4][4];
#pragma unroll
  for (int i = 0; i < 4; ++i)
#pragma unroll
    for (int j = 0; j < 4; ++j) acc[i][j] = 0.f;

  for (int kc = 0; kc < 117; ++kc) {
    const int seg   = kc / 13;
    const int cbase = (kc - seg * 13) * FBK;
    const int dy    = seg / 3 - 1;
    const int dx    = seg - (seg / 3) * 3 - 1;

#pragma unroll
    for (int rep = 0; rep < (FBM * FBK) / 256; ++rep) {
      const int idx = t + rep * 256;
      const int r  = idx >> 5;
      const int lk = idx & 31;
      const int m  = row0 + r;
      const int y  = m >> 7, x = m & 127;
      const int yy = y + dy, xx = x + dx;
      const int ci = cbase + lk;
      float v = 0.f;
      if ((unsigned)yy < HH && (unsigned)xx < WW && ci < CC)
        v = F[((size_t)(yy * WW + xx)) * CC + ci];
      Asf[lk][r] = v;
    }
#pragma unroll
    for (int rep = 0; rep < (FBK * FBN) / 256; ++rep) {
      const int idx = t + rep * 256;
      const int lk  = idx >> 6;
      const int nn  = idx & 63;
      const int ci  = cbase + lk;
      const int col = col0 + nn;
      float v = 0.f;
      if (ci < CC && col < CC)
        v = Wt[((size_t)(seg * CC + ci)) * CC + col];
      Bsf[lk][nn] = v;
    }
    __syncthreads();

#pragma unroll
    for (int lk = 0; lk < FBK; ++lk) {
      const float4 a4 = *(const float4*)(&Asf[lk][ty * 4]);
      const float4 b4 = *(const float4*)(&Bsf[lk][tx * 4]);
      const float av[4] = {a4.x, a4.y, a4.z, a4.w};
      const float bv[4] = {b4.x, b4.y, b4.z, b4.w};
#pragma unroll
      for (int i = 0; i < 4; ++i)
#pragma unroll
        for (int j = 0; j < 4; ++j)
          acc[i][j] = fmaf(av[i], bv[j], acc[i][j]);
    }
    __syncthreads();
  }

  const int col = col0 + tx * 4;
  if (col < CC) {
#pragma unroll
    for (int i = 0; i < 4; ++i) {
      float4 v = make_float4(acc[i][0], acc[i][1], acc[i][2], acc[i][3]);
      *(float4*)(&OM[((size_t)(row0 + ty * 4 + i)) * CC + col]) = v;
    }
  }
}

// ---------------------------------------------------------------------------
// Fused pooling: one thread per (roi, bin, group). Stage-1 bilinear of OM
// (2 offset chans for this group) -> scale -> deformable sample of features
// (2 chans). 4x the waves of the per-(roi,bin) version; 8 loads/thread.
// ---------------------------------------------------------------------------
__device__ __forceinline__ void bilin_setup(float y, float x,
                                            int& iy0, int& iy1, int& ix0, int& ix1,
                                            float& w00, float& w01, float& w10, float& w11) {
  const float y0f = floorf(y), x0f = floorf(x);
  const float wy = y - y0f, wx = x - x0f;   // unclamped, matches reference
  const int a = (int)y0f, b = (int)x0f;
  iy0 = min(max(a, 0), HH - 1);
  iy1 = min(max(a + 1, 0), HH - 1);
  ix0 = min(max(b, 0), WW - 1);
  ix1 = min(max(b + 1, 0), WW - 1);
  w00 = (1.f - wy) * (1.f - wx);
  w01 = (1.f - wy) * wx;
  w10 = wy * (1.f - wx);
  w11 = wy * wx;
}

template <typename TOM>
__global__ __launch_bounds__(256)
void psroi_pool_kernel(const float* __restrict__ F, const float* __restrict__ R,
                       const TOM* __restrict__ OM, float* __restrict__ out) {
  const int tid = blockIdx.x * 256 + threadIdx.x;
  if (tid >= NROI * NBIN * 4) return;
  const int g  = tid & 3;
  const int nb = tid >> 2;
  const int n  = nb / NBIN;
  const int b  = nb - n * NBIN;
  const int bi = b / PSK;
  const int bj = b - bi * PSK;

  const float rx1 = R[n * 5 + 1], ry1 = R[n * 5 + 2];
  const float rx2 = R[n * 5 + 3], ry2 = R[n * 5 + 4];

  const float x1 = rx1 * (1.f / 16.f);
  const float y1 = ry1 * (1.f / 16.f);
  const float x2 = (rx2 + 1.f) * (1.f / 16.f);
  const float y2 = (ry2 + 1.f) * (1.f / 16.f);
  const float bw = (x2 - x1) * (1.f / 7.f);
  const float bh = (y2 - y1) * (1.f / 7.f);
  const float cx = x1 + ((float)bj + 0.5f) * bw;
  const float cy = y1 + ((float)bi + 0.5f) * bh;

  // ---- stage 1: bilinear sample 2 offset channels from OM ----
  int iy0, iy1, ix0, ix1;
  float w00, w01, w10, w11;
  bilin_setup(cy, cx, iy0, iy1, ix0, ix1, w00, w01, w10, w11);

  const size_t c0 = (size_t)b * 8 + 2 * g;
  const size_t s00 = (size_t)(iy0 * WW + ix0) * CC + c0;
  const size_t s01 = (size_t)(iy0 * WW + ix1) * CC + c0;
  const size_t s10 = (size_t)(iy1 * WW + ix0) * CC + c0;
  const size_t s11 = (size_t)(iy1 * WW + ix1) * CC + c0;

  const float ox = w00 * (float)OM[s00]     + w01 * (float)OM[s01]
                 + w10 * (float)OM[s10]     + w11 * (float)OM[s11];
  const float oy = w00 * (float)OM[s00 + 1] + w01 * (float)OM[s01 + 1]
                 + w10 * (float)OM[s10 + 1] + w11 * (float)OM[s11 + 1];

  const float roiw = rx2 - rx1 + 1.f;
  const float roih = ry2 - ry1 + 1.f;
  const float sx = cx + ox * roiw * (LAMDA / 16.f);
  const float sy = cy + oy * roih * (LAMDA / 16.f);

  // ---- stage 2: deformable sample of features (2 channels) ----
  int jy0, jy1, jx0, jx1;
  float u00, u01, u10, u11;
  bilin_setup(sy, sx, jy0, jy1, jx0, jx1, u00, u01, u10, u11);

  const float2 q00 = *(const float2*)(F + (size_t)(jy0 * WW + jx0) * CC + c0);
  const float2 q01 = *(const float2*)(F + (size_t)(jy0 * WW + jx1) * CC + c0);
  const float2 q10 = *(const float2*)(F + (size_t)(jy1 * WW + jx0) * CC + c0);
  const float2 q11 = *(const float2*)(F + (size_t)(jy1 * WW + jx1) * CC + c0);

  const float v0 = u00 * q00.x + u01 * q01.x + u10 * q10.x + u11 * q11.x;
  const float v1 = u00 * q00.y + u01 * q01.y + u10 * q10.y + u11 * q11.y;

  out[((size_t)n * 8 + 2 * g + 0) * NBIN + b] = v0;
  out[((size_t)n * 8 + 2 * g + 1) * NBIN + b] = v1;
}

extern "C" void kernel_launch(void* const* d_in, const int* in_sizes, int n_in,
                              void* d_out, int out_size, void* d_ws, size_t ws_size,
                              hipStream_t stream) {
  const float* F  = (const float*)d_in[0];   // features [1,128,128,392] fp32
  const float* R  = (const float*)d_in[1];   // rois [2048,5] fp32
  const float* Wt = (const float*)d_in[2];   // conv_w [3,3,392,392] fp32
  float* out = (float*)d_out;                // [2048,8,7,7] fp32

  const size_t omBytes  = (size_t)NPIX * CC * sizeof(_Float16);            // 12.85 MB
  const size_t fhBytes  = (size_t)HPAD * HPAD * CPAD * sizeof(_Float16);   // 15.14 MB
  const size_t bthBytes = (size_t)NPADCO * SEGSTRIDE * sizeof(_Float16);   //  4.13 MB
  const size_t need = omBytes + fhBytes + bthBytes;                        // ~32.1 MB

  const int totalPool = NROI * NBIN * 4;

  if (ws_size >= need) {
    _Float16* OM  = (_Float16*)d_ws;
    _Float16* Fh  = (_Float16*)((char*)d_ws + omBytes);
    _Float16* Bth = (_Float16*)((char*)d_ws + omBytes + fhBytes);

    const int fTotal = HPAD * HPAD * (CPAD / 8);
    conv_f_kernel<<<(fTotal + 255) / 256, 256, 0, stream>>>(F, Fh);
    conv_w_kernel<<<9 * 14 * 16, 256, 0, stream>>>(Wt, Bth);

    dim3 g(NPIX / 128, NPADCO / 128);  // 128 x 4
    conv_mfma_kernel<<<g, 256, 0, stream>>>(Fh, Bth, OM);

    psroi_pool_kernel<_Float16><<<(totalPool + 255) / 256, 256, 0, stream>>>(F, R, OM, out);
  } else {
    // fallback: fp32 conv (round-1 path), needs 25.7 MB
    float* OM = (float*)d_ws;
    dim3 cgrid(NPIX / FBM, (CC + FBN - 1) / FBN);
    conv3x3_kernel<<<cgrid, 256, 0, stream>>>(F, Wt, OM);
    psroi_pool_kernel<float><<<(totalPool + 255) / 256, 256, 0, stream>>>(F, R, OM, out);
  }
}